// Round 11
// baseline (294.348 us; speedup 1.0000x reference)
//
#include <hip/hip_runtime.h>
#include <math.h>

#define NNS 16
#define CIN 64
#define COUT 64
#define CS 8
#define EPSB 1e-5f

typedef float f32x4 __attribute__((ext_vector_type(4)));
typedef short bf16x8 __attribute__((ext_vector_type(8)));

static __device__ __forceinline__ float rdlanef(float v, int l) {
    return __builtin_bit_cast(float, __builtin_amdgcn_readlane(__builtin_bit_cast(int, v), l));
}

// DPP cross-lane move (VALU pipe, not DS pipe).
template<int CTRL>
static __device__ __forceinline__ float dppf(float v) {
    return __builtin_bit_cast(float,
        __builtin_amdgcn_update_dpp(0, __builtin_bit_cast(int, v), CTRL, 0xf, 0xf, true));
}

// fp32 -> bf16 round-to-nearest-even (finite values)
static __device__ __forceinline__ short f2bf(float x) {
    unsigned b = __builtin_bit_cast(unsigned, x);
    b += 0x7FFFu + ((b >> 16) & 1u);
    return (short)(b >> 16);
}

// ---------------- Kernel 1: QKV projection, transposed MFMA ----------------
// D' = W^T (A-operand) x X^T (B-operand): per-lane frags identical to the
// verified round-10 staging, but D gives 4 CONSECUTIVE channels per lane
// -> float4 stores. Prologue loads W fully coalesced (16 lanes = one row)
// and scatters to frag-major bf16 LDS once per block.
__global__ __launch_bounds__(256, 2) void qkv_kernel(
    const float* __restrict__ x,
    const float* __restrict__ Wq, const float* __restrict__ bq,
    const float* __restrict__ Wk, const float* __restrict__ bk,
    const float* __restrict__ Wv, const float* __restrict__ bv,
    float* __restrict__ xq, float* __restrict__ xk, float* __restrict__ xv,
    int n)
{
    __shared__ short Wl[24 * 512];   // 24 frags x 512 bf16 = 24 KB

    const int tid  = threadIdx.x;
    const int lane = tid & 63;
    const int w    = tid >> 6;
    const int col  = lane & 15;   // point-within-tile
    const int kg   = lane >> 4;   // k-group / channel-quad selector

    // ---- coalesced prologue: W -> frag-major bf16 LDS ----
    // frag (m,t,h): lane l, elem j holds W[h*32+(l>>4)*8+j][t*16+(l&15)]
    const float* const Wm[3] = {Wq, Wk, Wv};
    #pragma unroll
    for (int m = 0; m < 3; ++m) {
        #pragma unroll
        for (int it = 0; it < 4; ++it) {
            const int vid = it * 256 + tid;        // f32x4 index within matrix
            const int u   = vid >> 4;              // weight row (k) 0..63
            const int c   = (vid & 15) * 4;        // weight col base 0..60
            const f32x4 v = *(const f32x4*)&Wm[m][u * 64 + c];
            const int t  = c >> 4;
            const int h  = u >> 5;
            const int f  = (m * 4 + t) * 2 + h;
            const int j  = u & 7;
            const int l0 = ((u >> 3) & 3) * 16 + (c & 15);
            #pragma unroll
            for (int q = 0; q < 4; ++q)
                Wl[f * 512 + (l0 + q) * 8 + j] = f2bf(v[q]);
        }
    }
    __syncthreads();

    // per-lane bias float4: channels t*16 + kg*4 .. +3
    const float* const bm[3] = {bq, bk, bv};
    f32x4 bias4[3][4];
    #pragma unroll
    for (int m = 0; m < 3; ++m)
        #pragma unroll
        for (int t = 0; t < 4; ++t)
            bias4[m][t] = *(const f32x4*)&bm[m][t * 16 + kg * 4];

    float* const om[3] = {xq, xk, xv};
    const int nchunks = (n + 63) >> 6;   // n is a multiple of 16
    for (int cb = blockIdx.x; cb < nchunks; cb += gridDim.x) {
        const int i0 = cb * 64 + w * 16;
        if (i0 >= n) continue;

        // B-frag (X^T): lane holds x[i0+col][k], k = h*32 + kg*8 + j
        const float* xr = x + (size_t)(i0 + col) * CIN + kg * 8;
        const f32x4 a0 = *(const f32x4*)(xr);
        const f32x4 a1 = *(const f32x4*)(xr + 4);
        const f32x4 a2 = *(const f32x4*)(xr + 32);
        const f32x4 a3 = *(const f32x4*)(xr + 36);
        bf16x8 B0, B1;
        #pragma unroll
        for (int j = 0; j < 4; ++j) {
            B0[j]     = f2bf(a0[j]);
            B0[j + 4] = f2bf(a1[j]);
            B1[j]     = f2bf(a2[j]);
            B1[j + 4] = f2bf(a3[j]);
        }

        f32x4 acc[3][4];
        #pragma unroll
        for (int m = 0; m < 3; ++m)
            #pragma unroll
            for (int t = 0; t < 4; ++t)
                acc[m][t] = bias4[m][t];
        #pragma unroll
        for (int m = 0; m < 3; ++m)
            #pragma unroll
            for (int t = 0; t < 4; ++t) {
                const int f = (m * 4 + t) * 2;
                const bf16x8 A0 = *(const bf16x8*)&Wl[(f + 0) * 512 + lane * 8];
                const bf16x8 A1 = *(const bf16x8*)&Wl[(f + 1) * 512 + lane * 8];
                acc[m][t] = __builtin_amdgcn_mfma_f32_16x16x32_bf16(A0, B0, acc[m][t], 0, 0, 0);
                acc[m][t] = __builtin_amdgcn_mfma_f32_16x16x32_bf16(A1, B1, acc[m][t], 0, 0, 0);
            }

        // store: point i0+col, channels t*16+kg*4..+3 -> one float4 each
        #pragma unroll
        for (int m = 0; m < 3; ++m)
            #pragma unroll
            for (int t = 0; t < 4; ++t)
                *(f32x4*)&om[m][(size_t)(i0 + col) * COUT + t * 16 + kg * 4] = acc[m][t];
    }
}

// ---------------- Kernel 2: fused neighbor attention, DPP butterfly (frozen) ----------------
__global__ __launch_bounds__(256) void fused_kernel(
    const float* __restrict__ p, const int* __restrict__ idx,
    const float* __restrict__ xq, const float* __restrict__ xk, const float* __restrict__ xv,
    const float* __restrict__ Wp1, const float* __restrict__ bp1,
    const float* __restrict__ bnp_g, const float* __restrict__ bnp_b,
    const float* __restrict__ bnp_m, const float* __restrict__ bnp_v,
    const float* __restrict__ Wp2, const float* __restrict__ bp2,
    const float* __restrict__ bnw1_g, const float* __restrict__ bnw1_b,
    const float* __restrict__ bnw1_m, const float* __restrict__ bnw1_v,
    const float* __restrict__ Ww1, const float* __restrict__ bw1,
    const float* __restrict__ bnw2_g, const float* __restrict__ bnw2_b,
    const float* __restrict__ bnw2_m, const float* __restrict__ bnw2_v,
    const float* __restrict__ Ww2, const float* __restrict__ bw2,
    float* __restrict__ out, int n)
{
    const int lane = threadIdx.x & 63;
    const int s    = (lane >> 3) & 7;   // owned slot after reduce-scatter
    const int r    = lane & 7;          // output-slot this channel consumes (c % 8)

    float wp1[9];
    #pragma unroll
    for (int t = 0; t < 9; ++t) wp1[t] = Wp1[t];
    float ap[3], cp[3];
    #pragma unroll
    for (int t = 0; t < 3; ++t) {
        const float a = bnp_g[t] * rsqrtf(bnp_v[t] + EPSB);
        ap[t] = a;
        cp[t] = (bp1[t] - bnp_m[t]) * a + bnp_b[t];
    }
    const float wp2_0 = Wp2[0 * COUT + lane];
    const float wp2_1 = Wp2[1 * COUT + lane];
    const float wp2_2 = Wp2[2 * COUT + lane];
    const float bp2c  = bp2[lane];
    const float a1 = bnw1_g[lane] * rsqrtf(bnw1_v[lane] + EPSB);
    const float c1 = bnw1_b[lane] - bnw1_m[lane] * a1;
    float w1p[8];
    #pragma unroll
    for (int t = 0; t < 8; ++t) w1p[t] = Ww1[lane * CS + (t ^ s)];
    const float a2s = bnw2_g[s] * rsqrtf(bnw2_v[s] + EPSB);
    const float c2s = bnw2_b[s] + (bw1[s] - bnw2_m[s]) * a2s;
    const float ww2l = Ww2[lane];
    const float bw2r = bw2[r];

    const int wid = __builtin_amdgcn_readfirstlane((int)(threadIdx.x >> 6));
    const int i = blockIdx.x * 4 + wid;
    if (i >= n) return;

    const int myidx = idx[i * NNS + (lane & 15)];
    const float xqc = xq[(size_t)i * COUT + lane];
    const float c1l = c1 - a1 * xqc;
    const float pix = p[i * 3 + 0];
    const float piy = p[i * 3 + 1];
    const float piz = p[i * 3 + 2];

    const float pjx = p[myidx * 3 + 0];
    const float pjy = p[myidx * 3 + 1];
    const float pjz = p[myidx * 3 + 2];

    float xkr[NNS], xvr[NNS];
    #pragma unroll
    for (int k = 0; k < NNS; ++k) {
        const int j = __builtin_amdgcn_readlane(myidx, k);
        xkr[k] = xk[(size_t)j * COUT + lane];
        xvr[k] = xv[(size_t)j * COUT + lane];
    }

    const float gx0 = pjx - pix, gx1 = pjy - piy, gx2 = pjz - piz;
    float h0 = fmaf(gx2, wp1[6], fmaf(gx1, wp1[3], gx0 * wp1[0]));
    float h1 = fmaf(gx2, wp1[7], fmaf(gx1, wp1[4], gx0 * wp1[1]));
    float h2 = fmaf(gx2, wp1[8], fmaf(gx1, wp1[5], gx0 * wp1[2]));
    h0 = fmaxf(0.f, fmaf(h0, ap[0], cp[0]));
    h1 = fmaxf(0.f, fmaf(h1, ap[1], cp[1]));
    h2 = fmaxf(0.f, fmaf(h2, ap[2], cp[2]));

    float y[NNS];
    float m = -INFINITY;

    #pragma unroll
    for (int k = 0; k < NNS; ++k) {
        const float hk0 = rdlanef(h0, k);
        const float hk1 = rdlanef(h1, k);
        const float hk2 = rdlanef(h2, k);
        const float pr = fmaf(hk2, wp2_2, fmaf(hk1, wp2_1, fmaf(hk0, wp2_0, bp2c)));
        const float wb = fmaxf(0.f, fmaf(xkr[k], a1, fmaf(pr, a1, c1l)));
        xvr[k] += pr;
        const float P0 = wb * w1p[0], P1 = wb * w1p[1], P2 = wb * w1p[2], P3 = wb * w1p[3];
        const float P4 = wb * w1p[4], P5 = wb * w1p[5], P6 = wb * w1p[6], P7 = wb * w1p[7];
        const float Q0 = P0 + dppf<0x128>(P1);
        const float Q2 = P2 + dppf<0x128>(P3);
        const float Q4 = P4 + dppf<0x128>(P5);
        const float Q6 = P6 + dppf<0x128>(P7);
        const float R0 = Q0 + __shfl_xor(Q2, 16, 64);
        const float R4 = Q4 + __shfl_xor(Q6, 16, 64);
        float T = R0 + __shfl_xor(R4, 32, 64);
        T += dppf<0xB1>(T);
        T += dppf<0x4E>(T);
        T += dppf<0x141>(T);
        const float wb2 = fmaxf(0.f, fmaf(T, a2s, c2s));
        float z = wb2 * ww2l;
        z += dppf<0x128>(z);
        z += __shfl_xor(z, 16, 64);
        z += __shfl_xor(z, 32, 64);
        const float yk = z + bw2r;
        y[k] = yk;
        m = fmaxf(m, yk);
    }

    float den = 0.f, acc = 0.f;
    #pragma unroll
    for (int k = 0; k < NNS; ++k) {
        const float e = __expf(y[k] - m);
        den += e;
        acc = fmaf(e, xvr[k], acc);
    }
    out[(size_t)i * COUT + lane] = acc / den;
}

extern "C" void kernel_launch(void* const* d_in, const int* in_sizes, int n_in,
                              void* d_out, int out_size, void* d_ws, size_t ws_size,
                              hipStream_t stream) {
    const float* p     = (const float*)d_in[0];
    const float* x     = (const float*)d_in[1];
    const int*   idx   = (const int*)  d_in[2];
    const float* Wq    = (const float*)d_in[3];
    const float* bq    = (const float*)d_in[4];
    const float* Wk    = (const float*)d_in[5];
    const float* bk    = (const float*)d_in[6];
    const float* Wv    = (const float*)d_in[7];
    const float* bv    = (const float*)d_in[8];
    const float* Wp1   = (const float*)d_in[9];
    const float* bp1   = (const float*)d_in[10];
    const float* bnp_g = (const float*)d_in[11];
    const float* bnp_b = (const float*)d_in[12];
    const float* bnp_m = (const float*)d_in[13];
    const float* bnp_v = (const float*)d_in[14];
    const float* Wp2   = (const float*)d_in[15];
    const float* bp2   = (const float*)d_in[16];
    const float* bnw1_g= (const float*)d_in[17];
    const float* bnw1_b= (const float*)d_in[18];
    const float* bnw1_m= (const float*)d_in[19];
    const float* bnw1_v= (const float*)d_in[20];
    const float* Ww1   = (const float*)d_in[21];
    const float* bw1   = (const float*)d_in[22];
    const float* bnw2_g= (const float*)d_in[23];
    const float* bnw2_b= (const float*)d_in[24];
    const float* bnw2_m= (const float*)d_in[25];
    const float* bnw2_v= (const float*)d_in[26];
    const float* Ww2   = (const float*)d_in[27];
    const float* bw2   = (const float*)d_in[28];

    const int n = in_sizes[0] / 3;   // N points

    float* xq = (float*)d_ws;
    float* xk = xq + (size_t)n * COUT;
    float* xv = xk + (size_t)n * COUT;

    hipLaunchKernelGGL(qkv_kernel, dim3(512), dim3(256), 0, stream,
                       x, Wq, bq, Wk, bk, Wv, bv, xq, xk, xv, n);
    hipLaunchKernelGGL(fused_kernel, dim3((n + 3) / 4), dim3(256), 0, stream,
                       p, idx, xq, xk, xv,
                       Wp1, bp1, bnp_g, bnp_b, bnp_m, bnp_v, Wp2, bp2,
                       bnw1_g, bnw1_b, bnw1_m, bnw1_v, Ww1, bw1,
                       bnw2_g, bnw2_b, bnw2_m, bnw2_v, Ww2, bw2,
                       (float*)d_out, n);
}

// Round 13
// 293.040 us; speedup vs baseline: 1.0045x; 1.0045x over previous
//
#include <hip/hip_runtime.h>
#include <math.h>

#define NNS 16
#define CIN 64
#define COUT 64
#define CS 8
#define EPSB 1e-5f

typedef float f32x4 __attribute__((ext_vector_type(4)));
typedef short bf16x8 __attribute__((ext_vector_type(8)));

static __device__ __forceinline__ float rdlanef(float v, int l) {
    return __builtin_bit_cast(float, __builtin_amdgcn_readlane(__builtin_bit_cast(int, v), l));
}

// DPP cross-lane move (VALU pipe, not DS pipe).
template<int CTRL>
static __device__ __forceinline__ float dppf(float v) {
    return __builtin_bit_cast(float,
        __builtin_amdgcn_update_dpp(0, __builtin_bit_cast(int, v), CTRL, 0xf, 0xf, true));
}

// fp32 -> bf16 round-to-nearest-even (finite values)
static __device__ __forceinline__ short f2bf(float x) {
    unsigned b = __builtin_bit_cast(unsigned, x);
    b += 0x7FFFu + ((b >> 16) & 1u);
    return (short)(b >> 16);
}

// ---------------- Kernel 1: QKV projection, transposed MFMA (frozen) ----------------
__global__ __launch_bounds__(256, 2) void qkv_kernel(
    const float* __restrict__ x,
    const float* __restrict__ Wq, const float* __restrict__ bq,
    const float* __restrict__ Wk, const float* __restrict__ bk,
    const float* __restrict__ Wv, const float* __restrict__ bv,
    float* __restrict__ xq, float* __restrict__ xk, float* __restrict__ xv,
    int n)
{
    __shared__ short Wl[24 * 512];   // 24 frags x 512 bf16 = 24 KB

    const int tid  = threadIdx.x;
    const int lane = tid & 63;
    const int w    = tid >> 6;
    const int col  = lane & 15;   // point-within-tile
    const int kg   = lane >> 4;   // k-group / channel-quad selector

    // coalesced prologue: W -> frag-major bf16 LDS
    const float* const Wm[3] = {Wq, Wk, Wv};
    #pragma unroll
    for (int m = 0; m < 3; ++m) {
        #pragma unroll
        for (int it = 0; it < 4; ++it) {
            const int vid = it * 256 + tid;
            const int u   = vid >> 4;
            const int c   = (vid & 15) * 4;
            const f32x4 v = *(const f32x4*)&Wm[m][u * 64 + c];
            const int t  = c >> 4;
            const int h  = u >> 5;
            const int f  = (m * 4 + t) * 2 + h;
            const int j  = u & 7;
            const int l0 = ((u >> 3) & 3) * 16 + (c & 15);
            #pragma unroll
            for (int q = 0; q < 4; ++q)
                Wl[f * 512 + (l0 + q) * 8 + j] = f2bf(v[q]);
        }
    }
    __syncthreads();

    const float* const bm[3] = {bq, bk, bv};
    f32x4 bias4[3][4];
    #pragma unroll
    for (int m = 0; m < 3; ++m)
        #pragma unroll
        for (int t = 0; t < 4; ++t)
            bias4[m][t] = *(const f32x4*)&bm[m][t * 16 + kg * 4];

    float* const om[3] = {xq, xk, xv};
    const int nchunks = (n + 63) >> 6;
    for (int cb = blockIdx.x; cb < nchunks; cb += gridDim.x) {
        const int i0 = cb * 64 + w * 16;
        if (i0 >= n) continue;

        const float* xr = x + (size_t)(i0 + col) * CIN + kg * 8;
        const f32x4 a0 = *(const f32x4*)(xr);
        const f32x4 a1 = *(const f32x4*)(xr + 4);
        const f32x4 a2 = *(const f32x4*)(xr + 32);
        const f32x4 a3 = *(const f32x4*)(xr + 36);
        bf16x8 B0, B1;
        #pragma unroll
        for (int j = 0; j < 4; ++j) {
            B0[j]     = f2bf(a0[j]);
            B0[j + 4] = f2bf(a1[j]);
            B1[j]     = f2bf(a2[j]);
            B1[j + 4] = f2bf(a3[j]);
        }

        f32x4 acc[3][4];
        #pragma unroll
        for (int m = 0; m < 3; ++m)
            #pragma unroll
            for (int t = 0; t < 4; ++t)
                acc[m][t] = bias4[m][t];
        #pragma unroll
        for (int m = 0; m < 3; ++m)
            #pragma unroll
            for (int t = 0; t < 4; ++t) {
                const int f = (m * 4 + t) * 2;
                const bf16x8 A0 = *(const bf16x8*)&Wl[(f + 0) * 512 + lane * 8];
                const bf16x8 A1 = *(const bf16x8*)&Wl[(f + 1) * 512 + lane * 8];
                acc[m][t] = __builtin_amdgcn_mfma_f32_16x16x32_bf16(A0, B0, acc[m][t], 0, 0, 0);
                acc[m][t] = __builtin_amdgcn_mfma_f32_16x16x32_bf16(A1, B1, acc[m][t], 0, 0, 0);
            }

        #pragma unroll
        for (int m = 0; m < 3; ++m)
            #pragma unroll
            for (int t = 0; t < 4; ++t)
                *(f32x4*)&om[m][(size_t)(i0 + col) * COUT + t * 16 + kg * 4] = acc[m][t];
    }
}

// ---------------- Kernel 2: fused neighbor attention, DPP butterfly ----------------
// ONLY change vs round 11: __launch_bounds__(256, 4) — 128-VGPR cap so
// xkr[16]/xvr[16]/y[16] live in registers instead of scratch (was VGPR=36,
// provably spilled).
__global__ __launch_bounds__(256, 4) void fused_kernel(
    const float* __restrict__ p, const int* __restrict__ idx,
    const float* __restrict__ xq, const float* __restrict__ xk, const float* __restrict__ xv,
    const float* __restrict__ Wp1, const float* __restrict__ bp1,
    const float* __restrict__ bnp_g, const float* __restrict__ bnp_b,
    const float* __restrict__ bnp_m, const float* __restrict__ bnp_v,
    const float* __restrict__ Wp2, const float* __restrict__ bp2,
    const float* __restrict__ bnw1_g, const float* __restrict__ bnw1_b,
    const float* __restrict__ bnw1_m, const float* __restrict__ bnw1_v,
    const float* __restrict__ Ww1, const float* __restrict__ bw1,
    const float* __restrict__ bnw2_g, const float* __restrict__ bnw2_b,
    const float* __restrict__ bnw2_m, const float* __restrict__ bnw2_v,
    const float* __restrict__ Ww2, const float* __restrict__ bw2,
    float* __restrict__ out, int n)
{
    const int lane = threadIdx.x & 63;
    const int s    = (lane >> 3) & 7;   // owned slot after reduce-scatter
    const int r    = lane & 7;          // output-slot this channel consumes (c % 8)

    float wp1[9];
    #pragma unroll
    for (int t = 0; t < 9; ++t) wp1[t] = Wp1[t];
    float ap[3], cp[3];
    #pragma unroll
    for (int t = 0; t < 3; ++t) {
        const float a = bnp_g[t] * rsqrtf(bnp_v[t] + EPSB);
        ap[t] = a;
        cp[t] = (bp1[t] - bnp_m[t]) * a + bnp_b[t];
    }
    const float wp2_0 = Wp2[0 * COUT + lane];
    const float wp2_1 = Wp2[1 * COUT + lane];
    const float wp2_2 = Wp2[2 * COUT + lane];
    const float bp2c  = bp2[lane];
    const float a1 = bnw1_g[lane] * rsqrtf(bnw1_v[lane] + EPSB);
    const float c1 = bnw1_b[lane] - bnw1_m[lane] * a1;
    float w1p[8];
    #pragma unroll
    for (int t = 0; t < 8; ++t) w1p[t] = Ww1[lane * CS + (t ^ s)];
    const float a2s = bnw2_g[s] * rsqrtf(bnw2_v[s] + EPSB);
    const float c2s = bnw2_b[s] + (bw1[s] - bnw2_m[s]) * a2s;
    const float ww2l = Ww2[lane];
    const float bw2r = bw2[r];

    const int wid = __builtin_amdgcn_readfirstlane((int)(threadIdx.x >> 6));
    const int i = blockIdx.x * 4 + wid;
    if (i >= n) return;

    const int myidx = idx[i * NNS + (lane & 15)];
    const float xqc = xq[(size_t)i * COUT + lane];
    const float c1l = c1 - a1 * xqc;
    const float pix = p[i * 3 + 0];
    const float piy = p[i * 3 + 1];
    const float piz = p[i * 3 + 2];

    const float pjx = p[myidx * 3 + 0];
    const float pjy = p[myidx * 3 + 1];
    const float pjz = p[myidx * 3 + 2];

    float xkr[NNS], xvr[NNS];
    #pragma unroll
    for (int k = 0; k < NNS; ++k) {
        const int j = __builtin_amdgcn_readlane(myidx, k);
        xkr[k] = xk[(size_t)j * COUT + lane];
        xvr[k] = xv[(size_t)j * COUT + lane];
    }

    const float gx0 = pjx - pix, gx1 = pjy - piy, gx2 = pjz - piz;
    float h0 = fmaf(gx2, wp1[6], fmaf(gx1, wp1[3], gx0 * wp1[0]));
    float h1 = fmaf(gx2, wp1[7], fmaf(gx1, wp1[4], gx0 * wp1[1]));
    float h2 = fmaf(gx2, wp1[8], fmaf(gx1, wp1[5], gx0 * wp1[2]));
    h0 = fmaxf(0.f, fmaf(h0, ap[0], cp[0]));
    h1 = fmaxf(0.f, fmaf(h1, ap[1], cp[1]));
    h2 = fmaxf(0.f, fmaf(h2, ap[2], cp[2]));

    float y[NNS];
    float m = -INFINITY;

    #pragma unroll
    for (int k = 0; k < NNS; ++k) {
        const float hk0 = rdlanef(h0, k);
        const float hk1 = rdlanef(h1, k);
        const float hk2 = rdlanef(h2, k);
        const float pr = fmaf(hk2, wp2_2, fmaf(hk1, wp2_1, fmaf(hk0, wp2_0, bp2c)));
        const float wb = fmaxf(0.f, fmaf(xkr[k], a1, fmaf(pr, a1, c1l)));
        xvr[k] += pr;
        const float P0 = wb * w1p[0], P1 = wb * w1p[1], P2 = wb * w1p[2], P3 = wb * w1p[3];
        const float P4 = wb * w1p[4], P5 = wb * w1p[5], P6 = wb * w1p[6], P7 = wb * w1p[7];
        const float Q0 = P0 + dppf<0x128>(P1);
        const float Q2 = P2 + dppf<0x128>(P3);
        const float Q4 = P4 + dppf<0x128>(P5);
        const float Q6 = P6 + dppf<0x128>(P7);
        const float R0 = Q0 + __shfl_xor(Q2, 16, 64);
        const float R4 = Q4 + __shfl_xor(Q6, 16, 64);
        float T = R0 + __shfl_xor(R4, 32, 64);
        T += dppf<0xB1>(T);
        T += dppf<0x4E>(T);
        T += dppf<0x141>(T);
        const float wb2 = fmaxf(0.f, fmaf(T, a2s, c2s));
        float z = wb2 * ww2l;
        z += dppf<0x128>(z);
        z += __shfl_xor(z, 16, 64);
        z += __shfl_xor(z, 32, 64);
        const float yk = z + bw2r;
        y[k] = yk;
        m = fmaxf(m, yk);
    }

    float den = 0.f, acc = 0.f;
    #pragma unroll
    for (int k = 0; k < NNS; ++k) {
        const float e = __expf(y[k] - m);
        den += e;
        acc = fmaf(e, xvr[k], acc);
    }
    out[(size_t)i * COUT + lane] = acc / den;
}

extern "C" void kernel_launch(void* const* d_in, const int* in_sizes, int n_in,
                              void* d_out, int out_size, void* d_ws, size_t ws_size,
                              hipStream_t stream) {
    const float* p     = (const float*)d_in[0];
    const float* x     = (const float*)d_in[1];
    const int*   idx   = (const int*)  d_in[2];
    const float* Wq    = (const float*)d_in[3];
    const float* bq    = (const float*)d_in[4];
    const float* Wk    = (const float*)d_in[5];
    const float* bk    = (const float*)d_in[6];
    const float* Wv    = (const float*)d_in[7];
    const float* bv    = (const float*)d_in[8];
    const float* Wp1   = (const float*)d_in[9];
    const float* bp1   = (const float*)d_in[10];
    const float* bnp_g = (const float*)d_in[11];
    const float* bnp_b = (const float*)d_in[12];
    const float* bnp_m = (const float*)d_in[13];
    const float* bnp_v = (const float*)d_in[14];
    const float* Wp2   = (const float*)d_in[15];
    const float* bp2   = (const float*)d_in[16];
    const float* bnw1_g= (const float*)d_in[17];
    const float* bnw1_b= (const float*)d_in[18];
    const float* bnw1_m= (const float*)d_in[19];
    const float* bnw1_v= (const float*)d_in[20];
    const float* Ww1   = (const float*)d_in[21];
    const float* bw1   = (const float*)d_in[22];
    const float* bnw2_g= (const float*)d_in[23];
    const float* bnw2_b= (const float*)d_in[24];
    const float* bnw2_m= (const float*)d_in[25];
    const float* bnw2_v= (const float*)d_in[26];
    const float* Ww2   = (const float*)d_in[27];
    const float* bw2   = (const float*)d_in[28];

    const int n = in_sizes[0] / 3;   // N points

    float* xq = (float*)d_ws;
    float* xk = xq + (size_t)n * COUT;
    float* xv = xk + (size_t)n * COUT;

    hipLaunchKernelGGL(qkv_kernel, dim3(512), dim3(256), 0, stream,
                       x, Wq, bq, Wk, bk, Wv, bv, xq, xk, xv, n);
    hipLaunchKernelGGL(fused_kernel, dim3((n + 3) / 4), dim3(256), 0, stream,
                       p, idx, xq, xk, xv,
                       Wp1, bp1, bnp_g, bnp_b, bnp_m, bnp_v, Wp2, bp2,
                       bnw1_g, bnw1_b, bnw1_m, bnw1_v, Ww1, bw1,
                       bnw2_g, bnw2_b, bnw2_m, bnw2_v, Ww2, bw2,
                       (float*)d_out, n);
}